// Round 1
// 5534.160 us; speedup vs baseline: 1.0715x; 1.0715x over previous
//
#include <hip/hip_runtime.h>
#include <math.h>

#define N_IMG 1024
#define C_IN 512
#define C_MID 1024
#define HW 7
#define SP 49
#define NCOLS (N_IMG*SP)      /* 50176 */
#define LDSROW 40             /* B tiles: 32 + 8 pad ushorts; 80 B row */
#define AROW 32               /* A tiles: linear 64 B rows (DMA target) */

typedef short bf16x8 __attribute__((ext_vector_type(8)));
typedef float f32x4  __attribute__((ext_vector_type(4)));

// async global->LDS DMA, 16 B per lane; LDS dest = wave-uniform base + lane*16
__device__ __forceinline__ void dma16(const void* g, void* l) {
    __builtin_amdgcn_global_load_lds(
        (const __attribute__((address_space(1))) void*)g,
        (__attribute__((address_space(3))) void*)l, 16, 0, 0);
}

// RNE fp32 -> (hi bf16, lo bf16) packed as lo<<16 | hi.
__device__ __forceinline__ unsigned splitpack(float v) {
    unsigned u  = __float_as_uint(v);
    unsigned hi = (u + 0x7FFFu + ((u >> 16) & 1u)) >> 16;
    float hf    = __uint_as_float(hi << 16);
    float d     = v - hf;                       // exact (Sterbenz)
    unsigned ud = __float_as_uint(d);
    unsigned lo = (ud + 0x7FFFu + ((ud >> 16) & 1u)) >> 16;
    return (hi & 0xFFFFu) | (lo << 16);
}

// ---------------------------------------------------------------------------
// Pre-pass: split X into packed hi|lo uints (same [n][c][p] layout).
__global__ __launch_bounds__(256)
void pack_x(const float* __restrict__ X, unsigned* __restrict__ Xpk)
{
    int i = blockIdx.x*256 + threadIdx.x;      // grid sized exactly
    Xpk[i] = splitpack(X[i]);
}

// Pre-pass: tile-order weight packs, separate hi/lo ushort arrays.
// Layout: [r][cc][bm][oc'(128)][c'(32)], each tile 4096 ushorts.
__global__ __launch_bounds__(256)
void pack_w1(const float* __restrict__ w, unsigned short* __restrict__ Wh,
             unsigned short* __restrict__ Wl)
{
    int e = blockIdx.x*256 + threadIdx.x;      // < 4718592
    int cp = e & 31, oc = (e>>5)&127, bm = (e>>12)&7, cc = (e>>15)&15, r = e>>19;
    float v = w[((size_t)(bm*128+oc)*512 + (cc*32+cp))*9 + r];
    unsigned pk = splitpack(v);
    Wh[e] = (unsigned short)(pk & 0xFFFFu);
    Wl[e] = (unsigned short)(pk >> 16);
}
__global__ __launch_bounds__(256)
void pack_w2(const float* __restrict__ w, unsigned short* __restrict__ Wh,
             unsigned short* __restrict__ Wl)
{
    int e = blockIdx.x*256 + threadIdx.x;      // < 9437184
    int cp = e & 31, oc = (e>>5)&127, bm = (e>>12)&7, cc = (e>>15)&31, r = e>>20;
    float v = w[((size_t)(bm*128+oc)*1024 + (cc*32+cp))*9 + r];
    unsigned pk = splitpack(v);
    Wh[e] = (unsigned short)(pk & 0xFFFFu);
    Wl[e] = (unsigned short)(pk >> 16);
}
__global__ __launch_bounds__(256)
void pack_wd(const float* __restrict__ w, unsigned short* __restrict__ Wh,
             unsigned short* __restrict__ Wl)
{
    int e = blockIdx.x*256 + threadIdx.x;      // < 524288
    int cp = e & 31, oc = (e>>5)&127, bm = (e>>12)&7, cc = e>>15;
    float v = w[(size_t)(bm*128+oc)*512 + cc*32+cp];
    unsigned pk = splitpack(v);
    Wh[e] = (unsigned short)(pk & 0xFFFFu);
    Wl[e] = (unsigned short)(pk >> 16);
}

// ---------------------------------------------------------------------------
// Tap-major conv GEMM on MFMA, split-bf16 (3-product fp32 emulation).
// A tiles: async global_load_lds DMA from tile-ordered pack into LINEAR LDS
// (64 B rows -> bank-uniform frag reads, no VGPR round-trip).
// B tiles: reg-staged shifted packed loads, hi/lo interleave, padded rows.
// Grid (8,392): bm FASTEST so the 8 blocks sharing one B panel are
// dispatch-adjacent -> B panel fetched from HBM once (L3-resident),
// instead of 8 bm-passes re-streaming the full 205 MB panel.
// ---------------------------------------------------------------------------
template<int MODE>
__global__ __launch_bounds__(256)
void conv_mfma(const unsigned* __restrict__ Bpk,   // packed [n][CS][49]
               const float* __restrict__ Xf,       // raw X (MODE1 shortcut)
               const unsigned short* __restrict__ Wh,
               const unsigned short* __restrict__ Wl,
               const unsigned short* __restrict__ Dh,
               const unsigned short* __restrict__ Dl,
               float* __restrict__ outF, unsigned* __restrict__ outU)
{
    constexpr int CS  = MODE ? C_MID : C_IN;
    constexpr int NCC = MODE ? 32 : 16;
    __shared__ __align__(16) unsigned short As_hi[128*AROW];
    __shared__ __align__(16) unsigned short As_lo[128*AROW];
    __shared__ __align__(16) unsigned short Bs_hi[128*LDSROW];
    __shared__ __align__(16) unsigned short Bs_lo[128*LDSROW];

    const int tid = threadIdx.x;
    const int bm = blockIdx.x, bn = blockIdx.y;

    const int ln = tid & 63;
    const int wv = tid >> 6;
    const int lm = ln & 15, lq = ln >> 4;
    const int wm = (wv & 1) * 64;
    const int wn = (wv >> 1) * 64;
    const int koff = lq * 8;

    // A DMA: wave wv covers ushorts [wv*1024, wv*1024+1024) of the 4096-ushort
    // tile; two calls of 1024 B each, lane ln supplies 16 B at +ln*16.
    const int go = wv*1024 + ln*8;             // ushort offset within tile

    // B staging: thread -> one column, 16 consecutive channels
    const int bcol = tid >> 1;
    const int half16 = (tid & 1) * 16;
    const int col = bn*128 + bcol;
    const int bnimg = col / SP;
    const int bp = col - bnimg*SP;
    const int by = bp / HW;
    const int bx = bp - by*HW;
    const int bo = bcol*LDSROW + half16;

    f32x4 acc[4][4];
    #pragma unroll
    for (int i = 0; i < 4; i++)
        #pragma unroll
        for (int j = 0; j < 4; j++)
            acc[i][j] = (f32x4){0.f, 0.f, 0.f, 0.f};

    for (int r = 0; r < 9; ++r) {
        const int t3 = r / 3;
        const int dy = t3 - 1;
        const int dx = (r - t3*3) - 1;
        const bool valid = ((unsigned)(by + dy) < (unsigned)HW) &&
                           ((unsigned)(bx + dx) < (unsigned)HW);
        const int pp = bp + dy*HW + dx;
        for (int cc = 0; cc < NCC; ++cc) {
            // ---- A stage: async DMA from tile-ordered pack ----
            {
                const size_t tb = ((size_t)((r*NCC + cc)*8 + bm) << 12);
                dma16(Wh + tb + go,       &As_hi[wv*1024]);
                dma16(Wh + tb + go + 512, &As_hi[wv*1024 + 512]);
                dma16(Wl + tb + go,       &As_lo[wv*1024]);
                dma16(Wl + tb + go + 512, &As_lo[wv*1024 + 512]);
            }
            // ---- B stage: shifted packed loads, imm offsets ----
            {
                unsigned v[16];
                if (valid) {
                    const unsigned* src =
                        Bpk + ((size_t)bnimg*CS + cc*32 + half16)*SP + pp;
                    #pragma unroll
                    for (int e = 0; e < 16; ++e) v[e] = src[e*SP];
                } else {
                    #pragma unroll
                    for (int e = 0; e < 16; ++e) v[e] = 0u;
                }
                unsigned hp[8], lp[8];
                #pragma unroll
                for (int j2 = 0; j2 < 8; ++j2) {
                    unsigned p0 = v[2*j2], p1 = v[2*j2+1];
                    hp[j2] = (p0 & 0xFFFFu) | (p1 << 16);
                    lp[j2] = (p0 >> 16) | (p1 & 0xFFFF0000u);
                }
                *(uint4*)&Bs_hi[bo]     = *(uint4*)&hp[0];
                *(uint4*)&Bs_hi[bo + 8] = *(uint4*)&hp[4];
                *(uint4*)&Bs_lo[bo]     = *(uint4*)&lp[0];
                *(uint4*)&Bs_lo[bo + 8] = *(uint4*)&lp[4];
            }
            __syncthreads();
            {
                bf16x8 ah[4], bh[4], al[4], bl[4];
                #pragma unroll
                for (int i = 0; i < 4; i++)
                    ah[i] = *(const bf16x8*)&As_hi[(wm + i*16 + lm)*AROW + koff];
                #pragma unroll
                for (int j = 0; j < 4; j++)
                    bh[j] = *(const bf16x8*)&Bs_hi[(wn + j*16 + lm)*LDSROW + koff];
                #pragma unroll
                for (int i = 0; i < 4; i++)
                    #pragma unroll
                    for (int j = 0; j < 4; j++)
                        acc[i][j] = __builtin_amdgcn_mfma_f32_16x16x32_bf16(
                            ah[i], bh[j], acc[i][j], 0, 0, 0);
                #pragma unroll
                for (int i = 0; i < 4; i++)
                    al[i] = *(const bf16x8*)&As_lo[(wm + i*16 + lm)*AROW + koff];
                #pragma unroll
                for (int i = 0; i < 4; i++)
                    #pragma unroll
                    for (int j = 0; j < 4; j++)
                        acc[i][j] = __builtin_amdgcn_mfma_f32_16x16x32_bf16(
                            al[i], bh[j], acc[i][j], 0, 0, 0);
                #pragma unroll
                for (int j = 0; j < 4; j++)
                    bl[j] = *(const bf16x8*)&Bs_lo[(wn + j*16 + lm)*LDSROW + koff];
                #pragma unroll
                for (int i = 0; i < 4; i++)
                    #pragma unroll
                    for (int j = 0; j < 4; j++)
                        acc[i][j] = __builtin_amdgcn_mfma_f32_16x16x32_bf16(
                            ah[i], bl[j], acc[i][j], 0, 0, 0);
            }
            __syncthreads();
        }
    }
    if (MODE == 1) {
        // shortcut: 1x1 conv over raw X (16 chunks, split in-kernel)
        for (int cc = 0; cc < 16; ++cc) {
            {
                const size_t tb = ((size_t)(cc*8 + bm) << 12);
                dma16(Dh + tb + go,       &As_hi[wv*1024]);
                dma16(Dh + tb + go + 512, &As_hi[wv*1024 + 512]);
                dma16(Dl + tb + go,       &As_lo[wv*1024]);
                dma16(Dl + tb + go + 512, &As_lo[wv*1024 + 512]);
            }
            {
                const float* src = Xf + ((size_t)bnimg*C_IN + cc*32 + half16)*SP + bp;
                unsigned v[16];
                #pragma unroll
                for (int e = 0; e < 16; ++e) v[e] = splitpack(src[e*SP]);
                unsigned hp[8], lp[8];
                #pragma unroll
                for (int j2 = 0; j2 < 8; ++j2) {
                    unsigned p0 = v[2*j2], p1 = v[2*j2+1];
                    hp[j2] = (p0 & 0xFFFFu) | (p1 << 16);
                    lp[j2] = (p0 >> 16) | (p1 & 0xFFFF0000u);
                }
                *(uint4*)&Bs_hi[bo]     = *(uint4*)&hp[0];
                *(uint4*)&Bs_hi[bo + 8] = *(uint4*)&hp[4];
                *(uint4*)&Bs_lo[bo]     = *(uint4*)&lp[0];
                *(uint4*)&Bs_lo[bo + 8] = *(uint4*)&lp[4];
            }
            __syncthreads();
            {
                bf16x8 ah[4], bh[4], al[4], bl[4];
                #pragma unroll
                for (int i = 0; i < 4; i++)
                    ah[i] = *(const bf16x8*)&As_hi[(wm + i*16 + lm)*AROW + koff];
                #pragma unroll
                for (int j = 0; j < 4; j++)
                    bh[j] = *(const bf16x8*)&Bs_hi[(wn + j*16 + lm)*LDSROW + koff];
                #pragma unroll
                for (int i = 0; i < 4; i++)
                    #pragma unroll
                    for (int j = 0; j < 4; j++)
                        acc[i][j] = __builtin_amdgcn_mfma_f32_16x16x32_bf16(
                            ah[i], bh[j], acc[i][j], 0, 0, 0);
                #pragma unroll
                for (int i = 0; i < 4; i++)
                    al[i] = *(const bf16x8*)&As_lo[(wm + i*16 + lm)*AROW + koff];
                #pragma unroll
                for (int i = 0; i < 4; i++)
                    #pragma unroll
                    for (int j = 0; j < 4; j++)
                        acc[i][j] = __builtin_amdgcn_mfma_f32_16x16x32_bf16(
                            al[i], bh[j], acc[i][j], 0, 0, 0);
                #pragma unroll
                for (int j = 0; j < 4; j++)
                    bl[j] = *(const bf16x8*)&Bs_lo[(wn + j*16 + lm)*LDSROW + koff];
                #pragma unroll
                for (int i = 0; i < 4; i++)
                    #pragma unroll
                    for (int j = 0; j < 4; j++)
                        acc[i][j] = __builtin_amdgcn_mfma_f32_16x16x32_bf16(
                            ah[i], bl[j], acc[i][j], 0, 0, 0);
            }
            __syncthreads();
        }
    }

    // ---- epilogue: relu; MODE0 packs h hi/lo uint, MODE1 stores fp32 ----
    // C/D layout (m89-verified): col = lane&15, row = (lane>>4)*4 + reg.
    #pragma unroll
    for (int j = 0; j < 4; j++) {
        const int gc = bn*128 + wn + j*16 + lm;
        const int n = gc / SP;
        const int p = gc - n*SP;
        #pragma unroll
        for (int i = 0; i < 4; i++) {
            #pragma unroll
            for (int r = 0; r < 4; r++) {
                const int m = bm*128 + wm + i*16 + lq*4 + r;
                float val = fmaxf(acc[i][j][r], 0.f);
                if (MODE == 0)
                    outU[((size_t)n*C_MID + m)*SP + p] = splitpack(val);
                else
                    outF[((size_t)n*C_MID + m)*SP + p] = val;
            }
        }
    }
}

// ---------------------------------------------------------------------------
__global__ __launch_bounds__(256)
void pool_kernel(const float* __restrict__ emb, float* __restrict__ flat)
{
    int n = blockIdx.x;
    for (int c = threadIdx.x; c < C_MID; c += 256) {
        const float* p = emb + ((size_t)n*C_MID + c)*SP;
        float s = 0.f;
        #pragma unroll
        for (int i = 0; i < SP; i++) s += p[i];
        flat[n*C_MID + c] = s / 49.0f;
    }
}

// ---------------------------------------------------------------------------
__global__ __launch_bounds__(64)
void head_kernel(const float* __restrict__ flat,
                 const float* __restrict__ cls_w, const float* __restrict__ cls_b,
                 const float* __restrict__ reg_w, const float* __restrict__ reg_b,
                 const float* __restrict__ props,
                 float* __restrict__ cls_out, float* __restrict__ reg_out,
                 float* __restrict__ pbox, float* __restrict__ pscore)
{
    int n = blockIdx.x;
    __shared__ float f[C_MID];
    __shared__ float logits[9];
    __shared__ float regs[36];
    for (int c = threadIdx.x; c < C_MID; c += 64) f[c] = flat[n*C_MID + c];
    __syncthreads();
    int o = threadIdx.x;
    if (o < 45) {
        const float* w = (o < 9) ? (cls_w + o*C_MID) : (reg_w + (o-9)*C_MID);
        float a = (o < 9) ? cls_b[o] : reg_b[o-9];
        for (int c = 0; c < C_MID; c++) a = fmaf(f[c], w[c], a);
        if (o < 9) { cls_out[n*9 + o] = a; logits[o] = a; }
        else       { reg_out[n*36 + (o-9)] = a; regs[o-9] = a; }
    }
    __syncthreads();
    if (o < 9) {
        float m = logits[0];
        for (int i = 1; i < 9; i++) m = fmaxf(m, logits[i]);
        float se = 0.f;
        for (int i = 0; i < 9; i++) se += expf(logits[i] - m);
        pscore[n*9 + o] = expf(logits[o] - m) / se;
        {
            #pragma clang fp contract(off)
            float x1 = props[n*4+0], y1 = props[n*4+1];
            float x2 = props[n*4+2], y2 = props[n*4+3];
            float pw = x2 - x1, ph = y2 - y1;
            float pcx = x1 + 0.5f*pw, pcy = y1 + 0.5f*ph;
            float dx = regs[o*4+0] / 10.0f;
            float dy = regs[o*4+1] / 10.0f;
            float dw = fminf(regs[o*4+2] / 5.0f, 4.135166556742356f);
            float dh = fminf(regs[o*4+3] / 5.0f, 4.135166556742356f);
            float ncx = dx*pw + pcx, ncy = dy*ph + pcy;
            float nw = expf(dw)*pw,  nh = expf(dh)*ph;
            float bx1 = ncx - 0.5f*nw, by1 = ncy - 0.5f*nh;
            float bx2 = ncx + 0.5f*nw, by2 = ncy + 0.5f*nh;
            bx1 = fminf(fmaxf(bx1, 0.f), 640.f);
            by1 = fminf(fmaxf(by1, 0.f), 384.f);
            bx2 = fminf(fmaxf(bx2, 0.f), 640.f);
            by2 = fminf(fmaxf(by2, 0.f), 384.f);
            float* dst = pbox + (n*9 + o)*4;
            dst[0] = bx1; dst[1] = by1; dst[2] = bx2; dst[3] = by2;
        }
    }
}

// ---------------------------------------------------------------------------
__global__ __launch_bounds__(1024)
void nms_kernel(const float* __restrict__ pbox, const float* __restrict__ pscore,
                float* __restrict__ dbox, float* __restrict__ dsc,
                float* __restrict__ dlab, float* __restrict__ dval)
{
    #pragma clang fp contract(off)
    const int b = blockIdx.x;
    const int tid = threadIdx.x;
    __shared__ unsigned long long mbuf[4096];
    __shared__ float s512[512];
    __shared__ int   id512[512];
    __shared__ float obx[512][4];
    __shared__ unsigned long long keepw[8];
    float* sc = (float*)mbuf;
    int*   si = (int*)(sc + 4096);
    const float NEG_INF = -__builtin_inff();

    for (int i = tid; i < 4096; i += 1024) {
        int p = i >> 3;
        int c = (i & 7) + 1;
        int n = b*512 + p;
        float s = pscore[n*9 + c];
        const float* bb = pbox + (n*9 + c)*4;
        float w = bb[2] - bb[0], h = bb[3] - bb[1];
        bool valid = (s > 0.05f) && (w >= 0.01f) && (h >= 0.01f);
        sc[i] = valid ? s : NEG_INF;
        si[i] = i;
    }
    __syncthreads();
    for (int k = 2; k <= 4096; k <<= 1) {
        for (int j = k >> 1; j > 0; j >>= 1) {
            for (int i = tid; i < 4096; i += 1024) {
                int ixj = i ^ j;
                if (ixj > i) {
                    float s1 = sc[i], s2 = sc[ixj];
                    int i1 = si[i], i2 = si[ixj];
                    bool before12 = (s1 > s2) || ((s1 == s2) && (i1 < i2));
                    bool up = ((i & k) == 0);
                    if (up ? !before12 : before12) {
                        sc[i] = s2; sc[ixj] = s1;
                        si[i] = i2; si[ixj] = i1;
                    }
                }
            }
            __syncthreads();
        }
    }
    if (tid < 512) {
        float s = sc[tid];
        int id = si[tid];
        s512[tid] = s;
        id512[tid] = id;
        int c = (id & 7) + 1;
        int n = b*512 + (id >> 3);
        float off = (float)c * 641.0f;
        const float* bb = pbox + (n*9 + c)*4;
        obx[tid][0] = bb[0] + off;
        obx[tid][1] = bb[1] + off;
        obx[tid][2] = bb[2] + off;
        obx[tid][3] = bb[3] + off;
    }
    __syncthreads();
    unsigned long long* mask = mbuf;
    for (int idx = tid; idx < 4096; idx += 1024) {
        int i = idx >> 3, w = idx & 7;
        float ax1 = obx[i][0], ay1 = obx[i][1], ax2 = obx[i][2], ay2 = obx[i][3];
        float aarea = (ax2 - ax1) * (ay2 - ay1);
        unsigned long long m = 0;
        int j0 = w << 6;
        for (int jj = 0; jj < 64; jj++) {
            int j = j0 + jj;
            if (j > i) {
                float bx1 = obx[j][0], by1 = obx[j][1];
                float bx2 = obx[j][2], by2 = obx[j][3];
                float barea = (bx2 - bx1) * (by2 - by1);
                float lx = fmaxf(ax1, bx1), ly = fmaxf(ay1, by1);
                float rx = fminf(ax2, bx2), ry = fminf(ay2, by2);
                float iw = fmaxf(rx - lx, 0.f), ih = fmaxf(ry - ly, 0.f);
                float inter = iw * ih;
                float iou = inter / fmaxf(aarea + barea - inter, 1e-8f);
                if (iou > 0.5f) m |= (1ull << jj);
            }
        }
        mask[(i << 3) + w] = m;
    }
    if (tid < 8) {
        unsigned long long kw = 0;
        for (int jj = 0; jj < 64; jj++)
            if (s512[(tid << 6) + jj] != NEG_INF) kw |= (1ull << jj);
        keepw[tid] = kw;
    }
    __syncthreads();
    if (tid == 0) {
        for (int i = 0; i < 512; i++) {
            if ((keepw[i >> 6] >> (i & 63)) & 1ull) {
                const unsigned long long* mi = mask + (i << 3);
                #pragma unroll
                for (int w = 0; w < 8; w++) keepw[w] &= ~mi[w];
            }
        }
        int cnt = 0;
        for (int i = 0; i < 512 && cnt < 100; i++) {
            if ((keepw[i >> 6] >> (i & 63)) & 1ull) {
                int id = id512[i];
                int c = (id & 7) + 1;
                int n = b*512 + (id >> 3);
                const float* bb = pbox + (n*9 + c)*4;
                float* db = dbox + (b*100 + cnt)*4;
                db[0] = bb[0]; db[1] = bb[1]; db[2] = bb[2]; db[3] = bb[3];
                dsc[b*100 + cnt] = s512[i];
                dlab[b*100 + cnt] = (float)c;
                dval[b*100 + cnt] = 1.0f;
                cnt++;
            }
        }
        for (; cnt < 100; cnt++) {
            float* db = dbox + (b*100 + cnt)*4;
            db[0] = 0.f; db[1] = 0.f; db[2] = 0.f; db[3] = 0.f;
            dsc[b*100 + cnt] = 0.f;
            dlab[b*100 + cnt] = 0.f;
            dval[b*100 + cnt] = 0.f;
        }
    }
}

// ---------------------------------------------------------------------------
extern "C" void kernel_launch(void* const* d_in, const int* in_sizes, int n_in,
                              void* d_out, int out_size, void* d_ws, size_t ws_size,
                              hipStream_t stream)
{
    const float* X      = (const float*)d_in[0];
    const float* props  = (const float*)d_in[1];
    const float* w1     = (const float*)d_in[2];
    const float* w2     = (const float*)d_in[3];
    const float* wd     = (const float*)d_in[4];
    const float* cls_w  = (const float*)d_in[5];
    const float* cls_b  = (const float*)d_in[6];
    const float* reg_w  = (const float*)d_in[7];
    const float* reg_b  = (const float*)d_in[8];

    float* out     = (float*)d_out;
    float* emb     = out;                        // 51380224 floats
    float* cls_out = out + 51380224;
    float* reg_out = cls_out + 9216;
    float* dbox    = reg_out + 36864;
    float* dsc     = dbox + 800;
    float* dlab    = dsc + 200;
    float* dval    = dlab + 200;

    // conv1-lifetime scratch inside the emb region (overwritten by conv2):
    unsigned* Xpk            = (unsigned*)out;             // 25,690,112 uints
    unsigned short* Wpk1h    = (unsigned short*)(out + 25690112); // 4,718,592 ush
    unsigned short* Wpk1l    = (unsigned short*)(out + 30408704); // 4,718,592 ush
    // (ends at float offset 35,127,296 < 51,380,224)

    char* wsb = (char*)d_ws;
    unsigned* h_u         = (unsigned*)(wsb);                       // 205,520,896 B
    unsigned short* Wpk2h = (unsigned short*)(wsb + 205520896);     // 18,874,368 B
    unsigned short* Wpk2l = (unsigned short*)(wsb + 224395264);     // 18,874,368 B
    unsigned short* Wpkdh = (unsigned short*)(wsb + 243269632);     //  1,048,576 B
    unsigned short* Wpkdl = (unsigned short*)(wsb + 244318208);     //  1,048,576 B
    float* flat           = (float*)(wsb + 245366784);              //  4,194,304 B
    float* pbox           = (float*)(wsb + 249561088);              //    147,456 B
    float* pscore         = (float*)(wsb + 249708544);              //     36,864 B

    pack_x <<<100352, 256, 0, stream>>>(X, Xpk);
    pack_w1<<<18432,  256, 0, stream>>>(w1, Wpk1h, Wpk1l);
    pack_w2<<<36864,  256, 0, stream>>>(w2, Wpk2h, Wpk2l);
    pack_wd<<<2048,   256, 0, stream>>>(wd, Wpkdh, Wpkdl);

    // bm fastest: the 8 blocks sharing one B panel run adjacently.
    dim3 cgrid(C_MID/128, NCOLS/128);
    conv_mfma<0><<<cgrid, 256, 0, stream>>>(Xpk, X, Wpk1h, Wpk1l,
                                            nullptr, nullptr, nullptr, h_u);
    conv_mfma<1><<<cgrid, 256, 0, stream>>>(h_u, X, Wpk2h, Wpk2l,
                                            Wpkdh, Wpkdl, emb, nullptr);
    pool_kernel<<<N_IMG, 256, 0, stream>>>(emb, flat);
    head_kernel<<<N_IMG, 64, 0, stream>>>(flat, cls_w, cls_b, reg_w, reg_b, props,
                                          cls_out, reg_out, pbox, pscore);
    nms_kernel<<<2, 1024, 0, stream>>>(pbox, pscore, dbox, dsc, dlab, dval);
}

// Round 2
// 5194.067 us; speedup vs baseline: 1.1417x; 1.0655x over previous
//
#include <hip/hip_runtime.h>
#include <math.h>

#define N_IMG 1024
#define C_IN 512
#define C_MID 1024
#define HW 7
#define SP 49
#define NCOLS (N_IMG*SP)      /* 50176 */
#define LDSROW 40             /* B tiles: 32 + 8 pad ushorts; 80 B row */
#define AROW 32               /* A tiles: linear 64 B rows (DMA target) */

typedef short bf16x8 __attribute__((ext_vector_type(8)));
typedef float f32x4  __attribute__((ext_vector_type(4)));

// async global->LDS DMA, 16 B per lane; LDS dest = wave-uniform base + lane*16
__device__ __forceinline__ void dma16(const void* g, void* l) {
    __builtin_amdgcn_global_load_lds(
        (const __attribute__((address_space(1))) void*)g,
        (__attribute__((address_space(3))) void*)l, 16, 0, 0);
}

// RNE fp32 -> (hi bf16, lo bf16) packed as lo<<16 | hi.
__device__ __forceinline__ unsigned splitpack(float v) {
    unsigned u  = __float_as_uint(v);
    unsigned hi = (u + 0x7FFFu + ((u >> 16) & 1u)) >> 16;
    float hf    = __uint_as_float(hi << 16);
    float d     = v - hf;                       // exact (Sterbenz)
    unsigned ud = __float_as_uint(d);
    unsigned lo = (ud + 0x7FFFu + ((ud >> 16) & 1u)) >> 16;
    return (hi & 0xFFFFu) | (lo << 16);
}

// ---------------------------------------------------------------------------
// Pre-pass: split X into packed hi|lo uints (same [n][c][p] layout).
__global__ __launch_bounds__(256)
void pack_x(const float* __restrict__ X, unsigned* __restrict__ Xpk)
{
    int i = blockIdx.x*256 + threadIdx.x;      // grid sized exactly
    Xpk[i] = splitpack(X[i]);
}

// Pre-pass: tile-order weight packs, separate hi/lo ushort arrays.
// Layout: [r][cc][bm][oc'(128)][c'(32)], each tile 4096 ushorts.
__global__ __launch_bounds__(256)
void pack_w1(const float* __restrict__ w, unsigned short* __restrict__ Wh,
             unsigned short* __restrict__ Wl)
{
    int e = blockIdx.x*256 + threadIdx.x;      // < 4718592
    int cp = e & 31, oc = (e>>5)&127, bm = (e>>12)&7, cc = (e>>15)&15, r = e>>19;
    float v = w[((size_t)(bm*128+oc)*512 + (cc*32+cp))*9 + r];
    unsigned pk = splitpack(v);
    Wh[e] = (unsigned short)(pk & 0xFFFFu);
    Wl[e] = (unsigned short)(pk >> 16);
}
__global__ __launch_bounds__(256)
void pack_w2(const float* __restrict__ w, unsigned short* __restrict__ Wh,
             unsigned short* __restrict__ Wl)
{
    int e = blockIdx.x*256 + threadIdx.x;      // < 9437184
    int cp = e & 31, oc = (e>>5)&127, bm = (e>>12)&7, cc = (e>>15)&31, r = e>>20;
    float v = w[((size_t)(bm*128+oc)*1024 + (cc*32+cp))*9 + r];
    unsigned pk = splitpack(v);
    Wh[e] = (unsigned short)(pk & 0xFFFFu);
    Wl[e] = (unsigned short)(pk >> 16);
}
__global__ __launch_bounds__(256)
void pack_wd(const float* __restrict__ w, unsigned short* __restrict__ Wh,
             unsigned short* __restrict__ Wl)
{
    int e = blockIdx.x*256 + threadIdx.x;      // < 524288
    int cp = e & 31, oc = (e>>5)&127, bm = (e>>12)&7, cc = e>>15;
    float v = w[(size_t)(bm*128+oc)*512 + cc*32+cp];
    unsigned pk = splitpack(v);
    Wh[e] = (unsigned short)(pk & 0xFFFFu);
    Wl[e] = (unsigned short)(pk >> 16);
}

// ---------------------------------------------------------------------------
// Channel-major conv GEMM on MFMA, split-bf16 (3-product fp32 emulation).
// LOOP ORDER cc OUTER / r INNER: the same 32-channel B slice (~25 KB) is
// re-read on 9 consecutive iterations -> reuse distance fits L1/L2 instead
// of the full 527 KB panel (the round-1 9.5 GB HBM over-fetch).
// A tiles: async global_load_lds DMA from tile-ordered pack, linear LDS rows.
// B tiles: reg-staged shifted packed loads, hi/lo interleave, padded rows.
// Grid: 1-D 3136 with XCD swizzle -- xcd=bid&7 owns bn in [xcd*49,xcd*49+49)
// (exactly 128 images), bm innermost so the 8 blocks sharing a B panel are
// adjacent ON THE SAME XCD L2.
// ---------------------------------------------------------------------------
template<int MODE>
__global__ __launch_bounds__(256)
void conv_mfma(const unsigned* __restrict__ Bpk,   // packed [n][CS][49]
               const float* __restrict__ Xf,       // raw X (MODE1 shortcut)
               const unsigned short* __restrict__ Wh,
               const unsigned short* __restrict__ Wl,
               const unsigned short* __restrict__ Dh,
               const unsigned short* __restrict__ Dl,
               float* __restrict__ outF, unsigned* __restrict__ outU)
{
    constexpr int CS  = MODE ? C_MID : C_IN;
    constexpr int NCC = MODE ? 32 : 16;
    __shared__ __align__(16) unsigned short As_hi[128*AROW];
    __shared__ __align__(16) unsigned short As_lo[128*AROW];
    __shared__ __align__(16) unsigned short Bs_hi[128*LDSROW];
    __shared__ __align__(16) unsigned short Bs_lo[128*LDSROW];

    const int tid = threadIdx.x;
    // XCD swizzle: same-panel (same bn) blocks land on one XCD, bm inner.
    const int bid  = blockIdx.x;
    const int xcd  = bid & 7;
    const int slot = bid >> 3;            // 0..391 within XCD
    const int bm   = slot & 7;
    const int bn   = xcd*49 + (slot >> 3);

    const int ln = tid & 63;
    const int wv = tid >> 6;
    const int lm = ln & 15, lq = ln >> 4;
    const int wm = (wv & 1) * 64;
    const int wn = (wv >> 1) * 64;
    const int koff = lq * 8;

    // A DMA: wave wv covers ushorts [wv*1024, wv*1024+1024) of the 4096-ushort
    // tile; two calls of 1024 B each, lane ln supplies 16 B at +ln*16.
    const int go = wv*1024 + ln*8;             // ushort offset within tile

    // B staging: thread -> one column, 16 consecutive channels
    const int bcol = tid >> 1;
    const int half16 = (tid & 1) * 16;
    const int col = bn*128 + bcol;
    const int bnimg = col / SP;
    const int bp = col - bnimg*SP;
    const int by = bp / HW;
    const int bx = bp - by*HW;
    const int bo = bcol*LDSROW + half16;

    f32x4 acc[4][4];
    #pragma unroll
    for (int i = 0; i < 4; i++)
        #pragma unroll
        for (int j = 0; j < 4; j++)
            acc[i][j] = (f32x4){0.f, 0.f, 0.f, 0.f};

    for (int cc = 0; cc < NCC; ++cc) {
        const unsigned* srcb = Bpk + ((size_t)bnimg*CS + cc*32 + half16)*SP;
        for (int r = 0; r < 9; ++r) {
            const int t3 = r / 3;
            const int dy = t3 - 1;
            const int dx = (r - t3*3) - 1;
            const bool valid = ((unsigned)(by + dy) < (unsigned)HW) &&
                               ((unsigned)(bx + dx) < (unsigned)HW);
            const int pp = bp + dy*HW + dx;
            // ---- A stage: async DMA from tile-ordered pack ----
            {
                const size_t tb = ((size_t)((r*NCC + cc)*8 + bm) << 12);
                dma16(Wh + tb + go,       &As_hi[wv*1024]);
                dma16(Wh + tb + go + 512, &As_hi[wv*1024 + 512]);
                dma16(Wl + tb + go,       &As_lo[wv*1024]);
                dma16(Wl + tb + go + 512, &As_lo[wv*1024 + 512]);
            }
            // ---- B stage: shifted packed loads, imm offsets ----
            {
                unsigned v[16];
                if (valid) {
                    const unsigned* src = srcb + pp;
                    #pragma unroll
                    for (int e = 0; e < 16; ++e) v[e] = src[e*SP];
                } else {
                    #pragma unroll
                    for (int e = 0; e < 16; ++e) v[e] = 0u;
                }
                unsigned hp[8], lp[8];
                #pragma unroll
                for (int j2 = 0; j2 < 8; ++j2) {
                    unsigned p0 = v[2*j2], p1 = v[2*j2+1];
                    hp[j2] = (p0 & 0xFFFFu) | (p1 << 16);
                    lp[j2] = (p0 >> 16) | (p1 & 0xFFFF0000u);
                }
                *(uint4*)&Bs_hi[bo]     = *(uint4*)&hp[0];
                *(uint4*)&Bs_hi[bo + 8] = *(uint4*)&hp[4];
                *(uint4*)&Bs_lo[bo]     = *(uint4*)&lp[0];
                *(uint4*)&Bs_lo[bo + 8] = *(uint4*)&lp[4];
            }
            __syncthreads();
            {
                bf16x8 ah[4], bh[4], al[4], bl[4];
                #pragma unroll
                for (int i = 0; i < 4; i++)
                    ah[i] = *(const bf16x8*)&As_hi[(wm + i*16 + lm)*AROW + koff];
                #pragma unroll
                for (int j = 0; j < 4; j++)
                    bh[j] = *(const bf16x8*)&Bs_hi[(wn + j*16 + lm)*LDSROW + koff];
                #pragma unroll
                for (int i = 0; i < 4; i++)
                    #pragma unroll
                    for (int j = 0; j < 4; j++)
                        acc[i][j] = __builtin_amdgcn_mfma_f32_16x16x32_bf16(
                            ah[i], bh[j], acc[i][j], 0, 0, 0);
                #pragma unroll
                for (int i = 0; i < 4; i++)
                    al[i] = *(const bf16x8*)&As_lo[(wm + i*16 + lm)*AROW + koff];
                #pragma unroll
                for (int i = 0; i < 4; i++)
                    #pragma unroll
                    for (int j = 0; j < 4; j++)
                        acc[i][j] = __builtin_amdgcn_mfma_f32_16x16x32_bf16(
                            al[i], bh[j], acc[i][j], 0, 0, 0);
                #pragma unroll
                for (int j = 0; j < 4; j++)
                    bl[j] = *(const bf16x8*)&Bs_lo[(wn + j*16 + lm)*LDSROW + koff];
                #pragma unroll
                for (int i = 0; i < 4; i++)
                    #pragma unroll
                    for (int j = 0; j < 4; j++)
                        acc[i][j] = __builtin_amdgcn_mfma_f32_16x16x32_bf16(
                            ah[i], bl[j], acc[i][j], 0, 0, 0);
            }
            __syncthreads();
        }
    }
    if (MODE == 1) {
        // shortcut: 1x1 conv over raw X (16 chunks, split in-kernel)
        for (int cc = 0; cc < 16; ++cc) {
            {
                const size_t tb = ((size_t)(cc*8 + bm) << 12);
                dma16(Dh + tb + go,       &As_hi[wv*1024]);
                dma16(Dh + tb + go + 512, &As_hi[wv*1024 + 512]);
                dma16(Dl + tb + go,       &As_lo[wv*1024]);
                dma16(Dl + tb + go + 512, &As_lo[wv*1024 + 512]);
            }
            {
                const float* src = Xf + ((size_t)bnimg*C_IN + cc*32 + half16)*SP + bp;
                unsigned v[16];
                #pragma unroll
                for (int e = 0; e < 16; ++e) v[e] = splitpack(src[e*SP]);
                unsigned hp[8], lp[8];
                #pragma unroll
                for (int j2 = 0; j2 < 8; ++j2) {
                    unsigned p0 = v[2*j2], p1 = v[2*j2+1];
                    hp[j2] = (p0 & 0xFFFFu) | (p1 << 16);
                    lp[j2] = (p0 >> 16) | (p1 & 0xFFFF0000u);
                }
                *(uint4*)&Bs_hi[bo]     = *(uint4*)&hp[0];
                *(uint4*)&Bs_hi[bo + 8] = *(uint4*)&hp[4];
                *(uint4*)&Bs_lo[bo]     = *(uint4*)&lp[0];
                *(uint4*)&Bs_lo[bo + 8] = *(uint4*)&lp[4];
            }
            __syncthreads();
            {
                bf16x8 ah[4], bh[4], al[4], bl[4];
                #pragma unroll
                for (int i = 0; i < 4; i++)
                    ah[i] = *(const bf16x8*)&As_hi[(wm + i*16 + lm)*AROW + koff];
                #pragma unroll
                for (int j = 0; j < 4; j++)
                    bh[j] = *(const bf16x8*)&Bs_hi[(wn + j*16 + lm)*LDSROW + koff];
                #pragma unroll
                for (int i = 0; i < 4; i++)
                    #pragma unroll
                    for (int j = 0; j < 4; j++)
                        acc[i][j] = __builtin_amdgcn_mfma_f32_16x16x32_bf16(
                            ah[i], bh[j], acc[i][j], 0, 0, 0);
                #pragma unroll
                for (int i = 0; i < 4; i++)
                    al[i] = *(const bf16x8*)&As_lo[(wm + i*16 + lm)*AROW + koff];
                #pragma unroll
                for (int i = 0; i < 4; i++)
                    #pragma unroll
                    for (int j = 0; j < 4; j++)
                        acc[i][j] = __builtin_amdgcn_mfma_f32_16x16x32_bf16(
                            al[i], bh[j], acc[i][j], 0, 0, 0);
                #pragma unroll
                for (int j = 0; j < 4; j++)
                    bl[j] = *(const bf16x8*)&Bs_lo[(wn + j*16 + lm)*LDSROW + koff];
                #pragma unroll
                for (int i = 0; i < 4; i++)
                    #pragma unroll
                    for (int j = 0; j < 4; j++)
                        acc[i][j] = __builtin_amdgcn_mfma_f32_16x16x32_bf16(
                            ah[i], bl[j], acc[i][j], 0, 0, 0);
            }
            __syncthreads();
        }
    }

    // ---- epilogue: relu; MODE0 packs h hi/lo uint, MODE1 stores fp32 ----
    // C/D layout (m89-verified): col = lane&15, row = (lane>>4)*4 + reg.
    #pragma unroll
    for (int j = 0; j < 4; j++) {
        const int gc = bn*128 + wn + j*16 + lm;
        const int n = gc / SP;
        const int p = gc - n*SP;
        #pragma unroll
        for (int i = 0; i < 4; i++) {
            #pragma unroll
            for (int r = 0; r < 4; r++) {
                const int m = bm*128 + wm + i*16 + lq*4 + r;
                float val = fmaxf(acc[i][j][r], 0.f);
                if (MODE == 0)
                    outU[((size_t)n*C_MID + m)*SP + p] = splitpack(val);
                else
                    outF[((size_t)n*C_MID + m)*SP + p] = val;
            }
        }
    }
}

// ---------------------------------------------------------------------------
__global__ __launch_bounds__(256)
void pool_kernel(const float* __restrict__ emb, float* __restrict__ flat)
{
    int n = blockIdx.x;
    for (int c = threadIdx.x; c < C_MID; c += 256) {
        const float* p = emb + ((size_t)n*C_MID + c)*SP;
        float s = 0.f;
        #pragma unroll
        for (int i = 0; i < SP; i++) s += p[i];
        flat[n*C_MID + c] = s / 49.0f;
    }
}

// ---------------------------------------------------------------------------
__global__ __launch_bounds__(64)
void head_kernel(const float* __restrict__ flat,
                 const float* __restrict__ cls_w, const float* __restrict__ cls_b,
                 const float* __restrict__ reg_w, const float* __restrict__ reg_b,
                 const float* __restrict__ props,
                 float* __restrict__ cls_out, float* __restrict__ reg_out,
                 float* __restrict__ pbox, float* __restrict__ pscore)
{
    int n = blockIdx.x;
    __shared__ float f[C_MID];
    __shared__ float logits[9];
    __shared__ float regs[36];
    for (int c = threadIdx.x; c < C_MID; c += 64) f[c] = flat[n*C_MID + c];
    __syncthreads();
    int o = threadIdx.x;
    if (o < 45) {
        const float* w = (o < 9) ? (cls_w + o*C_MID) : (reg_w + (o-9)*C_MID);
        float a = (o < 9) ? cls_b[o] : reg_b[o-9];
        for (int c = 0; c < C_MID; c++) a = fmaf(f[c], w[c], a);
        if (o < 9) { cls_out[n*9 + o] = a; logits[o] = a; }
        else       { reg_out[n*36 + (o-9)] = a; regs[o-9] = a; }
    }
    __syncthreads();
    if (o < 9) {
        float m = logits[0];
        for (int i = 1; i < 9; i++) m = fmaxf(m, logits[i]);
        float se = 0.f;
        for (int i = 0; i < 9; i++) se += expf(logits[i] - m);
        pscore[n*9 + o] = expf(logits[o] - m) / se;
        {
            #pragma clang fp contract(off)
            float x1 = props[n*4+0], y1 = props[n*4+1];
            float x2 = props[n*4+2], y2 = props[n*4+3];
            float pw = x2 - x1, ph = y2 - y1;
            float pcx = x1 + 0.5f*pw, pcy = y1 + 0.5f*ph;
            float dx = regs[o*4+0] / 10.0f;
            float dy = regs[o*4+1] / 10.0f;
            float dw = fminf(regs[o*4+2] / 5.0f, 4.135166556742356f);
            float dh = fminf(regs[o*4+3] / 5.0f, 4.135166556742356f);
            float ncx = dx*pw + pcx, ncy = dy*ph + pcy;
            float nw = expf(dw)*pw,  nh = expf(dh)*ph;
            float bx1 = ncx - 0.5f*nw, by1 = ncy - 0.5f*nh;
            float bx2 = ncx + 0.5f*nw, by2 = ncy + 0.5f*nh;
            bx1 = fminf(fmaxf(bx1, 0.f), 640.f);
            by1 = fminf(fmaxf(by1, 0.f), 384.f);
            bx2 = fminf(fmaxf(bx2, 0.f), 640.f);
            by2 = fminf(fmaxf(by2, 0.f), 384.f);
            float* dst = pbox + (n*9 + o)*4;
            dst[0] = bx1; dst[1] = by1; dst[2] = bx2; dst[3] = by2;
        }
    }
}

// ---------------------------------------------------------------------------
__global__ __launch_bounds__(1024)
void nms_kernel(const float* __restrict__ pbox, const float* __restrict__ pscore,
                float* __restrict__ dbox, float* __restrict__ dsc,
                float* __restrict__ dlab, float* __restrict__ dval)
{
    #pragma clang fp contract(off)
    const int b = blockIdx.x;
    const int tid = threadIdx.x;
    __shared__ unsigned long long mbuf[4096];
    __shared__ float s512[512];
    __shared__ int   id512[512];
    __shared__ float obx[512][4];
    __shared__ unsigned long long keepw[8];
    float* sc = (float*)mbuf;
    int*   si = (int*)(sc + 4096);
    const float NEG_INF = -__builtin_inff();

    for (int i = tid; i < 4096; i += 1024) {
        int p = i >> 3;
        int c = (i & 7) + 1;
        int n = b*512 + p;
        float s = pscore[n*9 + c];
        const float* bb = pbox + (n*9 + c)*4;
        float w = bb[2] - bb[0], h = bb[3] - bb[1];
        bool valid = (s > 0.05f) && (w >= 0.01f) && (h >= 0.01f);
        sc[i] = valid ? s : NEG_INF;
        si[i] = i;
    }
    __syncthreads();
    for (int k = 2; k <= 4096; k <<= 1) {
        for (int j = k >> 1; j > 0; j >>= 1) {
            for (int i = tid; i < 4096; i += 1024) {
                int ixj = i ^ j;
                if (ixj > i) {
                    float s1 = sc[i], s2 = sc[ixj];
                    int i1 = si[i], i2 = si[ixj];
                    bool before12 = (s1 > s2) || ((s1 == s2) && (i1 < i2));
                    bool up = ((i & k) == 0);
                    if (up ? !before12 : before12) {
                        sc[i] = s2; sc[ixj] = s1;
                        si[i] = i2; si[ixj] = i1;
                    }
                }
            }
            __syncthreads();
        }
    }
    if (tid < 512) {
        float s = sc[tid];
        int id = si[tid];
        s512[tid] = s;
        id512[tid] = id;
        int c = (id & 7) + 1;
        int n = b*512 + (id >> 3);
        float off = (float)c * 641.0f;
        const float* bb = pbox + (n*9 + c)*4;
        obx[tid][0] = bb[0] + off;
        obx[tid][1] = bb[1] + off;
        obx[tid][2] = bb[2] + off;
        obx[tid][3] = bb[3] + off;
    }
    __syncthreads();
    unsigned long long* mask = mbuf;
    for (int idx = tid; idx < 4096; idx += 1024) {
        int i = idx >> 3, w = idx & 7;
        float ax1 = obx[i][0], ay1 = obx[i][1], ax2 = obx[i][2], ay2 = obx[i][3];
        float aarea = (ax2 - ax1) * (ay2 - ay1);
        unsigned long long m = 0;
        int j0 = w << 6;
        for (int jj = 0; jj < 64; jj++) {
            int j = j0 + jj;
            if (j > i) {
                float bx1 = obx[j][0], by1 = obx[j][1];
                float bx2 = obx[j][2], by2 = obx[j][3];
                float barea = (bx2 - bx1) * (by2 - by1);
                float lx = fmaxf(ax1, bx1), ly = fmaxf(ay1, by1);
                float rx = fminf(ax2, bx2), ry = fminf(ay2, by2);
                float iw = fmaxf(rx - lx, 0.f), ih = fmaxf(ry - ly, 0.f);
                float inter = iw * ih;
                float iou = inter / fmaxf(aarea + barea - inter, 1e-8f);
                if (iou > 0.5f) m |= (1ull << jj);
            }
        }
        mask[(i << 3) + w] = m;
    }
    if (tid < 8) {
        unsigned long long kw = 0;
        for (int jj = 0; jj < 64; jj++)
            if (s512[(tid << 6) + jj] != NEG_INF) kw |= (1ull << jj);
        keepw[tid] = kw;
    }
    __syncthreads();
    if (tid == 0) {
        for (int i = 0; i < 512; i++) {
            if ((keepw[i >> 6] >> (i & 63)) & 1ull) {
                const unsigned long long* mi = mask + (i << 3);
                #pragma unroll
                for (int w = 0; w < 8; w++) keepw[w] &= ~mi[w];
            }
        }
        int cnt = 0;
        for (int i = 0; i < 512 && cnt < 100; i++) {
            if ((keepw[i >> 6] >> (i & 63)) & 1ull) {
                int id = id512[i];
                int c = (id & 7) + 1;
                int n = b*512 + (id >> 3);
                const float* bb = pbox + (n*9 + c)*4;
                float* db = dbox + (b*100 + cnt)*4;
                db[0] = bb[0]; db[1] = bb[1]; db[2] = bb[2]; db[3] = bb[3];
                dsc[b*100 + cnt] = s512[i];
                dlab[b*100 + cnt] = (float)c;
                dval[b*100 + cnt] = 1.0f;
                cnt++;
            }
        }
        for (; cnt < 100; cnt++) {
            float* db = dbox + (b*100 + cnt)*4;
            db[0] = 0.f; db[1] = 0.f; db[2] = 0.f; db[3] = 0.f;
            dsc[b*100 + cnt] = 0.f;
            dlab[b*100 + cnt] = 0.f;
            dval[b*100 + cnt] = 0.f;
        }
    }
}

// ---------------------------------------------------------------------------
extern "C" void kernel_launch(void* const* d_in, const int* in_sizes, int n_in,
                              void* d_out, int out_size, void* d_ws, size_t ws_size,
                              hipStream_t stream)
{
    const float* X      = (const float*)d_in[0];
    const float* props  = (const float*)d_in[1];
    const float* w1     = (const float*)d_in[2];
    const float* w2     = (const float*)d_in[3];
    const float* wd     = (const float*)d_in[4];
    const float* cls_w  = (const float*)d_in[5];
    const float* cls_b  = (const float*)d_in[6];
    const float* reg_w  = (const float*)d_in[7];
    const float* reg_b  = (const float*)d_in[8];

    float* out     = (float*)d_out;
    float* emb     = out;                        // 51380224 floats
    float* cls_out = out + 51380224;
    float* reg_out = cls_out + 9216;
    float* dbox    = reg_out + 36864;
    float* dsc     = dbox + 800;
    float* dlab    = dsc + 200;
    float* dval    = dlab + 200;

    // conv1-lifetime scratch inside the emb region (overwritten by conv2):
    unsigned* Xpk            = (unsigned*)out;             // 25,690,112 uints
    unsigned short* Wpk1h    = (unsigned short*)(out + 25690112); // 4,718,592 ush
    unsigned short* Wpk1l    = (unsigned short*)(out + 30408704); // 4,718,592 ush
    // (ends at float offset 35,127,296 < 51,380,224)

    char* wsb = (char*)d_ws;
    unsigned* h_u         = (unsigned*)(wsb);                       // 205,520,896 B
    unsigned short* Wpk2h = (unsigned short*)(wsb + 205520896);     // 18,874,368 B
    unsigned short* Wpk2l = (unsigned short*)(wsb + 224395264);     // 18,874,368 B
    unsigned short* Wpkdh = (unsigned short*)(wsb + 243269632);     //  1,048,576 B
    unsigned short* Wpkdl = (unsigned short*)(wsb + 244318208);     //  1,048,576 B
    float* flat           = (float*)(wsb + 245366784);              //  4,194,304 B
    float* pbox           = (float*)(wsb + 249561088);              //    147,456 B
    float* pscore         = (float*)(wsb + 249708544);              //     36,864 B

    pack_x <<<100352, 256, 0, stream>>>(X, Xpk);
    pack_w1<<<18432,  256, 0, stream>>>(w1, Wpk1h, Wpk1l);
    pack_w2<<<36864,  256, 0, stream>>>(w2, Wpk2h, Wpk2l);
    pack_wd<<<2048,   256, 0, stream>>>(wd, Wpkdh, Wpkdl);

    // 1-D grid, XCD-swizzled inside the kernel (bn panels pinned per XCD).
    conv_mfma<0><<<3136, 256, 0, stream>>>(Xpk, X, Wpk1h, Wpk1l,
                                           nullptr, nullptr, nullptr, h_u);
    conv_mfma<1><<<3136, 256, 0, stream>>>(h_u, X, Wpk2h, Wpk2l,
                                           Wpkdh, Wpkdl, emb, nullptr);
    pool_kernel<<<N_IMG, 256, 0, stream>>>(emb, flat);
    head_kernel<<<N_IMG, 64, 0, stream>>>(flat, cls_w, cls_b, reg_w, reg_b, props,
                                          cls_out, reg_out, pbox, pscore);
    nms_kernel<<<2, 1024, 0, stream>>>(pbox, pscore, dbox, dsc, dlab, dval);
}